// Round 1
// baseline (467.181 us; speedup 1.0000x reference)
//
#include <hip/hip_runtime.h>
#include <stdint.h>

typedef unsigned short u16;
typedef short short8 __attribute__((ext_vector_type(8)));
typedef float f32x4 __attribute__((ext_vector_type(4)));

// Problem sizes: B=16384, D=768, E=124 (pad 128), C=6, E*C=744 (pad 768)
#define NB 16384

// ---- workspace layout (bytes) ----
#define OFF_XHI      0ull            // bf16 [16384][768]
#define OFF_XLO      25165824ull     // bf16 [16384][768]
#define OFF_LCLS     0ull            // aliases XHI: bf16 [16384][768] class logits (cols 0..743 real)
#define OFF_LWE      25165824ull     // aliases XLO: f32 [16384][128] which_expert
#define OFF_LEW      33554432ull     // f32 [16384][128] expert-weight logits
#define OFF_BT1      50331648ull     // bf16 [1536][768]  (cls_w1^T ; ew_w1^T)
#define OFF_BTWE_HI  52690944ull     // bf16 [768][768]
#define OFF_BTWE_LO  53870592ull
#define OFF_BT2CLS   55050240ull     // bf16 [768][768] (744 real rows, padded w/ 0)
#define OFF_BT2EW    56229888ull     // bf16 [128][768]
#define OFF_BT2WE_HI 56426496ull
#define OFF_BT2WE_LO 56623104ull
#define OFF_B1CE     56819712ull     // f32 [1536]
#define OFF_B1WE     56825856ull     // f32 [768]
#define OFF_B2CLS    56828928ull     // f32 [768]
#define OFF_B2EW     56832000ull     // f32 [128]
#define OFF_B2WE     56832512ull     // f32 [128]
#define OFF_HCLSEW   56833024ull     // bf16 [16384][1536] gelu(h) for cls|ew
#define OFF_HWE_HI   107164672ull    // bf16 [16384][768]
#define OFF_HWE_LO   132330496ull    // bf16 [16384][768]
#define WS_NEED      157496320ull

__device__ __forceinline__ u16 f2bf(float f) {          // RNE f32->bf16
  uint32_t u = __float_as_uint(f);
  u += 0x7fffu + ((u >> 16) & 1u);
  return (u16)(u >> 16);
}
__device__ __forceinline__ float bf2f(u16 h) {
  return __uint_as_float(((uint32_t)h) << 16);
}
__device__ __forceinline__ void g2l16(const u16* g, u16* l) {
  // async global->LDS, 16B per lane; LDS dest must be wave-uniform base (+lane*16 by HW)
  __builtin_amdgcn_global_load_lds(
      (__attribute__((address_space(1))) void*)(u16*)g,
      (__attribute__((address_space(3))) void*)l, 16, 0, 0);
}

// ---------------- x -> (hi, lo) bf16 split ----------------
__global__ void cvt_x_split(const float* __restrict__ x, u16* __restrict__ xhi,
                            u16* __restrict__ xlo) {
  int i = blockIdx.x * 256 + threadIdx.x;          // grid sized exactly: 12288*256 = 16384*768/4
  float4 v = ((const float4*)x)[i];
  ushort4 h, l;
  h.x = f2bf(v.x); l.x = f2bf(v.x - bf2f(h.x));
  h.y = f2bf(v.y); l.y = f2bf(v.y - bf2f(h.y));
  h.z = f2bf(v.z); l.z = f2bf(v.z - bf2f(h.z));
  h.w = f2bf(v.w); l.w = f2bf(v.w - bf2f(h.w));
  ((ushort4*)xhi)[i] = h;
  ((ushort4*)xlo)[i] = l;
}

// ---------------- weight prep: transpose to B^T[N][K] bf16 (+pads, splits, bias concat) ----------------
__global__ void prep_weights(
    const float* __restrict__ cls_w1, const float* __restrict__ cls_b1,
    const float* __restrict__ cls_w2, const float* __restrict__ cls_b2,
    const float* __restrict__ we_w1,  const float* __restrict__ we_b1,
    const float* __restrict__ we_w2,  const float* __restrict__ we_b2,
    const float* __restrict__ ew_w1,  const float* __restrict__ ew_b1,
    const float* __restrict__ ew_w2,  const float* __restrict__ ew_b2,
    u16* BT1, u16* BTwe_hi, u16* BTwe_lo,
    u16* BT2cls, u16* BT2ew, u16* BT2we_hi, u16* BT2we_lo,
    float* b1ce, float* b1we, float* b2cls, float* b2ew, float* b2we) {
  int id = blockIdx.x * 256 + threadIdx.x;
  if (id < 1536 * 768) {                       // BT1: [cls_w1^T ; ew_w1^T]
    int n = id / 768, k = id - n * 768;
    float v = (n < 768) ? cls_w1[k * 768 + n] : ew_w1[k * 768 + (n - 768)];
    BT1[id] = f2bf(v);
    return;
  }
  id -= 1536 * 768;
  if (id < 768 * 768) {                        // we_w1^T split
    int n = id / 768, k = id - n * 768;
    float v = we_w1[k * 768 + n];
    u16 h = f2bf(v);
    BTwe_hi[id] = h;
    BTwe_lo[id] = f2bf(v - bf2f(h));
    return;
  }
  id -= 768 * 768;
  if (id < 768 * 768) {                        // cls_w2^T, pad 744->768 with 0
    int n = id / 768, k = id - n * 768;
    BT2cls[id] = f2bf((n < 744) ? cls_w2[k * 744 + n] : 0.f);
    return;
  }
  id -= 768 * 768;
  if (id < 128 * 768) {                        // ew_w2^T, pad 124->128
    int n = id / 768, k = id - n * 768;
    BT2ew[id] = f2bf((n < 124) ? ew_w2[k * 124 + n] : 0.f);
    return;
  }
  id -= 128 * 768;
  if (id < 128 * 768) {                        // we_w2^T split, pad
    int n = id / 768, k = id - n * 768;
    float v = (n < 124) ? we_w2[k * 124 + n] : 0.f;
    u16 h = f2bf(v);
    BT2we_hi[id] = h;
    BT2we_lo[id] = f2bf(v - bf2f(h));
    return;
  }
  id -= 128 * 768;
  if (id < 1536) { b1ce[id] = (id < 768) ? cls_b1[id] : ew_b1[id - 768]; return; }
  id -= 1536;
  if (id < 768) { b1we[id] = we_b1[id]; return; }
  id -= 768;
  if (id < 768) { b2cls[id] = (id < 744) ? cls_b2[id] : 0.f; return; }
  id -= 768;
  if (id < 128) { b2ew[id] = (id < 124) ? ew_b2[id] : 0.f; return; }
  id -= 128;
  if (id < 128) { b2we[id] = (id < 124) ? we_b2[id] : 0.f; return; }
}

// ---------------- m97-pattern GEMM: C[M,N] = sum_p A_p[M,K] * B_p^T  (+bias, epilogue) ----------------
// A row-major bf16 (lda), B^T given N-major [N][K] bf16 (ldb=K). Tiles 128x128, BK=64, 256 thr (4 waves 2x2).
// MODE 0: gelu -> bf16    MODE 1: fp32   MODE 2: gelu -> bf16 hi + bf16 lo   MODE 3: bf16 (no gelu)
template <int MODE>
__global__ __launch_bounds__(256, 3) void gemm_k(
    const u16* A0, const u16* A1, const u16* A2, int lda,
    const u16* B0, const u16* B1, const u16* B2,
    int npass, int K, const float* __restrict__ bias,
    void* out0, void* out1, int ldc) {
  __shared__ u16 sA[128 * 64];   // [m][k], 64 bf16/row (128B rows, global_load_lds-contiguous)
  __shared__ u16 sB[128 * 64];   // [n][k]
  const int tid = threadIdx.x;
  const int lane = tid & 63;
  const int wv = tid >> 6;
  const int wr = wv >> 1, wc = wv & 1;   // wave 2x2 -> 64x64 each
  const int bm = blockIdx.y * 128;
  const int bn = blockIdx.x * 128;
  const int sr = lane >> 3;              // staging sub-row 0..7
  const int sc = (lane & 7) * 8;         // staging col (elements)

  f32x4 acc[4][4];
#pragma unroll
  for (int i = 0; i < 4; i++)
#pragma unroll
    for (int j = 0; j < 4; j++) acc[i][j] = f32x4{0.f, 0.f, 0.f, 0.f};

  for (int p = 0; p < npass; ++p) {
    const u16* A = (p == 0) ? A0 : ((p == 1) ? A1 : A2);
    const u16* Bp = (p == 0) ? B0 : ((p == 1) ? B1 : B2);
    const u16* gA = A + (size_t)(bm + wv * 32 + sr) * lda + sc;
    const u16* gB = Bp + (size_t)(bn + wv * 32 + sr) * K + sc;
    u16* lA = sA + (wv * 32) * 64;   // wave-uniform LDS bases
    u16* lB = sB + (wv * 32) * 64;
    for (int kt = 0; kt < K; kt += 64) {
#pragma unroll
      for (int s = 0; s < 4; ++s) {
        g2l16(gA + (size_t)(s * 8) * lda + kt, lA + s * 8 * 64);
        g2l16(gB + (size_t)(s * 8) * K + kt, lB + s * 8 * 64);
      }
      __syncthreads();   // drains vmcnt (global_load_lds) then barrier
#pragma unroll
      for (int ks = 0; ks < 2; ++ks) {
        short8 av[4], bv[4];
#pragma unroll
        for (int i = 0; i < 4; i++)
          av[i] = *(const short8*)(sA + (wr * 64 + i * 16 + (lane & 15)) * 64 + ks * 32 + (lane >> 4) * 8);
#pragma unroll
        for (int j = 0; j < 4; j++)
          bv[j] = *(const short8*)(sB + (wc * 64 + j * 16 + (lane & 15)) * 64 + ks * 32 + (lane >> 4) * 8);
#pragma unroll
        for (int i = 0; i < 4; i++)
#pragma unroll
          for (int j = 0; j < 4; j++)
            acc[i][j] = __builtin_amdgcn_mfma_f32_16x16x32_bf16(av[i], bv[j], acc[i][j], 0, 0, 0);
      }
      __syncthreads();
    }
  }
  // epilogue: C/D layout col=lane&15, row=(lane>>4)*4+r  [verified m89/m91]
#pragma unroll
  for (int j = 0; j < 4; j++) {
    const int col = bn + wc * 64 + j * 16 + (lane & 15);
    const float bs = bias[col];
#pragma unroll
    for (int i = 0; i < 4; i++) {
      const int row0 = bm + wr * 64 + i * 16 + (lane >> 4) * 4;
#pragma unroll
      for (int r = 0; r < 4; r++) {
        float v = acc[i][j][r] + bs;
        const size_t idx = (size_t)(row0 + r) * ldc + col;
        if (MODE == 1) {
          ((float*)out0)[idx] = v;
        } else if (MODE == 3) {
          ((u16*)out0)[idx] = f2bf(v);
        } else {
          float g = 0.5f * v * (1.0f + erff(v * 0.70710678118654752f));  // exact GELU
          u16 h = f2bf(g);
          ((u16*)out0)[idx] = h;
          if (MODE == 2) ((u16*)out1)[idx] = f2bf(g - bf2f(h));
        }
      }
    }
  }
}

// ---------------- finalize: per-row top-k threshold, masked softmax, class mixture ----------------
__global__ __launch_bounds__(64) void finalize(
    const u16* __restrict__ Lcls,   // bf16 [B][768], expert e classes at cols e*6..e*6+5
    const float* __restrict__ Lwe,  // f32 [B][128] which_expert (pads = 0, ignored)
    const float* __restrict__ Lew,  // f32 [B][128]
    const int* __restrict__ nexp, float* __restrict__ out) {
  const int b = blockIdx.x;
  const int t = threadIdx.x;
  __shared__ float s[128];
  const float NEG = -3.0e38f;
  const float w0 = (t < 124) ? Lwe[(size_t)b * 128 + t] : NEG;
  const float w1 = (t < 60) ? Lwe[(size_t)b * 128 + t + 64] : NEG;
  s[t] = w0;
  s[t + 64] = w1;
  __syncthreads();
  // bitonic ascending sort of 128 values, 1 wave, 2 elems/thread
  for (int k = 2; k <= 128; k <<= 1) {
    for (int j = k >> 1; j > 0; j >>= 1) {
#pragma unroll
      for (int h = 0; h < 2; ++h) {
        int i = t + h * 64;
        int ixj = i ^ j;
        if (ixj > i) {
          float a = s[i], c = s[ixj];
          bool up = ((i & k) == 0);
          if ((a > c) == up) { s[i] = c; s[ixj] = a; }
        }
      }
      __syncthreads();
    }
  }
  int n = nexp[b];
  n = n < 1 ? 1 : (n > 124 ? 124 : n);
  const float thr = s[128 - n];                 // n-th largest (ref: sorted_desc[n-1])
  // masked expert softmax (mask: which < thr -> -inf)
  float l0 = (t < 124 && w0 >= thr) ? Lew[(size_t)b * 128 + t] : NEG;
  float l1 = (t < 60 && w1 >= thr) ? Lew[(size_t)b * 128 + t + 64] : NEG;
  float mx = fmaxf(l0, l1);
#pragma unroll
  for (int o = 32; o > 0; o >>= 1) mx = fmaxf(mx, __shfl_xor(mx, o, 64));
  float e0 = (l0 > NEG) ? __expf(l0 - mx) : 0.f;
  float e1 = (l1 > NEG) ? __expf(l1 - mx) : 0.f;
  float S = e0 + e1;
#pragma unroll
  for (int o = 32; o > 0; o >>= 1) S += __shfl_xor(S, o, 64);
  float a0 = 0, a1 = 0, a2 = 0, a3 = 0, a4 = 0, a5 = 0;
#pragma unroll
  for (int h = 0; h < 2; ++h) {
    int e = t + h * 64;
    float we = h ? e1 : e0;
    if (we > 0.f) {
      const u16* lp = Lcls + (size_t)b * 768 + e * 6;
      float c0 = bf2f(lp[0]), c1 = bf2f(lp[1]), c2 = bf2f(lp[2]);
      float c3 = bf2f(lp[3]), c4 = bf2f(lp[4]), c5 = bf2f(lp[5]);
      float m = fmaxf(fmaxf(fmaxf(c0, c1), fmaxf(c2, c3)), fmaxf(c4, c5));
      float p0 = __expf(c0 - m), p1 = __expf(c1 - m), p2 = __expf(c2 - m);
      float p3 = __expf(c3 - m), p4 = __expf(c4 - m), p5 = __expf(c5 - m);
      float inv = we / (p0 + p1 + p2 + p3 + p4 + p5);
      a0 += p0 * inv; a1 += p1 * inv; a2 += p2 * inv;
      a3 += p3 * inv; a4 += p4 * inv; a5 += p5 * inv;
    }
  }
#pragma unroll
  for (int o = 32; o > 0; o >>= 1) {
    a0 += __shfl_xor(a0, o, 64); a1 += __shfl_xor(a1, o, 64);
    a2 += __shfl_xor(a2, o, 64); a3 += __shfl_xor(a3, o, 64);
    a4 += __shfl_xor(a4, o, 64); a5 += __shfl_xor(a5, o, 64);
  }
  if (t < 6) {
    float v = (t == 0) ? a0 : (t == 1) ? a1 : (t == 2) ? a2 : (t == 3) ? a3 : (t == 4) ? a4 : a5;
    out[(size_t)b * 6 + t] = v / S;   // == (sum p*w) / (sum w), matches ref's explicit division
  }
}

__global__ void fill_sentinel(float* out, int n, float v) {
  int i = blockIdx.x * 256 + threadIdx.x;
  if (i < n) out[i] = v;
}

extern "C" void kernel_launch(void* const* d_in, const int* in_sizes, int n_in,
                              void* d_out, int out_size, void* d_ws, size_t ws_size,
                              hipStream_t stream) {
  const float* x = (const float*)d_in[0];
  const int* nexp = (const int*)d_in[1];
  const float* cls_w1 = (const float*)d_in[2];
  const float* cls_b1 = (const float*)d_in[3];
  const float* cls_w2 = (const float*)d_in[4];
  const float* cls_b2 = (const float*)d_in[5];
  const float* we_w1 = (const float*)d_in[6];
  const float* we_b1 = (const float*)d_in[7];
  const float* we_w2 = (const float*)d_in[8];
  const float* we_b2 = (const float*)d_in[9];
  const float* ew_w1 = (const float*)d_in[10];
  const float* ew_b1 = (const float*)d_in[11];
  const float* ew_w2 = (const float*)d_in[12];
  const float* ew_b2 = (const float*)d_in[13];
  float* out = (float*)d_out;
  char* ws = (char*)d_ws;

  if (ws_size < WS_NEED) {  // diagnosable failure: absmax will be ~12345
    fill_sentinel<<<(out_size + 255) / 256, 256, 0, stream>>>(out, out_size, 12345.0f);
    return;
  }

  u16* xhi = (u16*)(ws + OFF_XHI);
  u16* xlo = (u16*)(ws + OFF_XLO);
  u16* Lcls = (u16*)(ws + OFF_LCLS);
  float* Lwe = (float*)(ws + OFF_LWE);
  float* Lew = (float*)(ws + OFF_LEW);
  u16* BT1 = (u16*)(ws + OFF_BT1);
  u16* BTwe_hi = (u16*)(ws + OFF_BTWE_HI);
  u16* BTwe_lo = (u16*)(ws + OFF_BTWE_LO);
  u16* BT2cls = (u16*)(ws + OFF_BT2CLS);
  u16* BT2ew = (u16*)(ws + OFF_BT2EW);
  u16* BT2we_hi = (u16*)(ws + OFF_BT2WE_HI);
  u16* BT2we_lo = (u16*)(ws + OFF_BT2WE_LO);
  float* b1ce = (float*)(ws + OFF_B1CE);
  float* b1we = (float*)(ws + OFF_B1WE);
  float* b2cls = (float*)(ws + OFF_B2CLS);
  float* b2ew = (float*)(ws + OFF_B2EW);
  float* b2we = (float*)(ws + OFF_B2WE);
  u16* h_clsew = (u16*)(ws + OFF_HCLSEW);
  u16* h_we_hi = (u16*)(ws + OFF_HWE_HI);
  u16* h_we_lo = (u16*)(ws + OFF_HWE_LO);

  cvt_x_split<<<12288, 256, 0, stream>>>(x, xhi, xlo);
  prep_weights<<<9997, 256, 0, stream>>>(cls_w1, cls_b1, cls_w2, cls_b2,
                                         we_w1, we_b1, we_w2, we_b2,
                                         ew_w1, ew_b1, ew_w2, ew_b2,
                                         BT1, BTwe_hi, BTwe_lo, BT2cls, BT2ew,
                                         BT2we_hi, BT2we_lo, b1ce, b1we, b2cls, b2ew, b2we);
  // fc1 for cls+ew (N=1536), gelu -> bf16
  gemm_k<0><<<dim3(12, 128), 256, 0, stream>>>(xhi, nullptr, nullptr, 768,
                                               BT1, nullptr, nullptr, 1, 768,
                                               b1ce, h_clsew, nullptr, 1536);
  // fc1 for we, 3-term split-bf16 (hi*Whi + lo*Whi + hi*Wlo), gelu -> bf16 hi+lo
  gemm_k<2><<<dim3(6, 128), 256, 0, stream>>>(xhi, xlo, xhi, 768,
                                              BTwe_hi, BTwe_hi, BTwe_lo, 3, 768,
                                              b1we, h_we_hi, h_we_lo, 768);
  // fc2 cls (N=768 padded) -> bf16 class logits (overwrites xhi region; x no longer needed)
  gemm_k<3><<<dim3(6, 128), 256, 0, stream>>>(h_clsew, nullptr, nullptr, 1536,
                                              BT2cls, nullptr, nullptr, 1, 768,
                                              b2cls, Lcls, nullptr, 768);
  // fc2 ew (N=128 padded) -> f32
  gemm_k<1><<<dim3(1, 128), 256, 0, stream>>>(h_clsew + 768, nullptr, nullptr, 1536,
                                              BT2ew, nullptr, nullptr, 1, 768,
                                              b2ew, Lew, nullptr, 128);
  // fc2 we, 3-term split -> f32 which_expert
  gemm_k<1><<<dim3(1, 128), 256, 0, stream>>>(h_we_hi, h_we_lo, h_we_hi, 768,
                                              BT2we_hi, BT2we_hi, BT2we_lo, 3, 768,
                                              b2we, Lwe, nullptr, 128);
  finalize<<<NB, 64, 0, stream>>>(Lcls, Lwe, Lew, nexp, out);
}

// Round 2
// 390.978 us; speedup vs baseline: 1.1949x; 1.1949x over previous
//
#include <hip/hip_runtime.h>
#include <stdint.h>

typedef unsigned short u16;
typedef short short8 __attribute__((ext_vector_type(8)));
typedef float f32x4 __attribute__((ext_vector_type(4)));

// Problem sizes: B=16384, D=768, E=124 (pad 128), C=6, E*C=744 (pad 768)
#define NB 16384

// ---- workspace layout (bytes) ----
#define OFF_XHI      0ull            // bf16 [16384][768]
#define OFF_XLO      25165824ull     // bf16 [16384][768]
#define OFF_LCLS     0ull            // aliases XHI: bf16 [16384][768] class logits (cols 0..743 real)
#define OFF_LWE      25165824ull     // aliases XLO: f32 [16384][128] which_expert
#define OFF_LEW      33554432ull     // f32 [16384][128] expert-weight logits
#define OFF_BT1      50331648ull     // bf16 [1536][768]  (cls_w1^T ; ew_w1^T)
#define OFF_BTWE_HI  52690944ull     // bf16 [768][768]
#define OFF_BTWE_LO  53870592ull
#define OFF_BT2CLS   55050240ull     // bf16 [768][768] (744 real rows, padded w/ 0)
#define OFF_BT2EW    56229888ull     // bf16 [128][768]
#define OFF_BT2WE_HI 56426496ull
#define OFF_BT2WE_LO 56623104ull
#define OFF_B1CE     56819712ull     // f32 [1536]
#define OFF_B1WE     56825856ull     // f32 [768]
#define OFF_B2CLS    56828928ull     // f32 [768]
#define OFF_B2EW     56832000ull     // f32 [128]
#define OFF_B2WE     56832512ull     // f32 [128]
#define OFF_HCLSEW   56833024ull     // bf16 [16384][1536] gelu(h) for cls|ew
#define OFF_HWE_HI   107164672ull    // bf16 [16384][768]
#define OFF_HWE_LO   132330496ull    // bf16 [16384][768]
#define WS_NEED      157496320ull

__device__ __forceinline__ u16 f2bf(float f) {          // RNE f32->bf16
  uint32_t u = __float_as_uint(f);
  u += 0x7fffu + ((u >> 16) & 1u);
  return (u16)(u >> 16);
}
__device__ __forceinline__ float bf2f(u16 h) {
  return __uint_as_float(((uint32_t)h) << 16);
}
__device__ __forceinline__ void g2l16(const u16* g, u16* l) {
  // async global->LDS, 16B/lane; LDS dest = wave-uniform base + lane*16 (HW rule)
  __builtin_amdgcn_global_load_lds(
      (__attribute__((address_space(1))) void*)(u16*)g,
      (__attribute__((address_space(3))) void*)l, 16, 0, 0);
}

// ---------------- x -> (hi, lo) bf16 split ----------------
__global__ void cvt_x_split(const float* __restrict__ x, u16* __restrict__ xhi,
                            u16* __restrict__ xlo) {
  int i = blockIdx.x * 256 + threadIdx.x;          // 12288*256 = 16384*768/4 exact
  float4 v = ((const float4*)x)[i];
  ushort4 h, l;
  h.x = f2bf(v.x); l.x = f2bf(v.x - bf2f(h.x));
  h.y = f2bf(v.y); l.y = f2bf(v.y - bf2f(h.y));
  h.z = f2bf(v.z); l.z = f2bf(v.z - bf2f(h.z));
  h.w = f2bf(v.w); l.w = f2bf(v.w - bf2f(h.w));
  ((ushort4*)xhi)[i] = h;
  ((ushort4*)xlo)[i] = l;
}

// ---------------- LDS-tiled weight transpose: W[K=768][N] -> BT[Npad][768] bf16 ----------------
__global__ void transpose_w(
    const float* __restrict__ cls_w1, const float* __restrict__ ew_w1,
    const float* __restrict__ we_w1,  const float* __restrict__ cls_w2,
    const float* __restrict__ ew_w2,  const float* __restrict__ we_w2,
    u16* BT1, u16* BTwe_hi, u16* BTwe_lo,
    u16* BT2cls, u16* BT2ew, u16* BT2we_hi, u16* BT2we_lo) {
  const float* src; int N; u16* dhi; u16* dlo = nullptr;
  switch (blockIdx.z) {
    case 0: src = cls_w1; N = 768; dhi = BT1; break;
    case 1: src = ew_w1;  N = 768; dhi = BT1 + 768 * 768; break;
    case 2: src = we_w1;  N = 768; dhi = BTwe_hi; dlo = BTwe_lo; break;
    case 3: src = cls_w2; N = 744; dhi = BT2cls; break;
    case 4: src = ew_w2;  N = 124; dhi = BT2ew; break;
    default: src = we_w2; N = 124; dhi = BT2we_hi; dlo = BT2we_lo; break;
  }
  const int Npad = (N + 127) & ~127;
  const int n0 = blockIdx.y * 64;
  if (n0 >= Npad) return;
  const int k0 = blockIdx.x * 64;
  const int tx = threadIdx.x & 63, tg = threadIdx.x >> 6;
  __shared__ float t[64][65];
#pragma unroll
  for (int r = 0; r < 16; ++r) {
    int k = tg * 16 + r;
    int n = n0 + tx;
    t[k][tx] = (n < N) ? src[(size_t)(k0 + k) * N + n] : 0.f;   // coalesced read
  }
  __syncthreads();
#pragma unroll
  for (int r = 0; r < 16; ++r) {
    int n = n0 + tg * 16 + r;
    if (n < Npad) {
      float v = t[tx][tg * 16 + r];
      u16 h = f2bf(v);
      dhi[(size_t)n * 768 + k0 + tx] = h;                       // coalesced write
      if (dlo) dlo[(size_t)n * 768 + k0 + tx] = f2bf(v - bf2f(h));
    }
  }
}

// ---------------- bias prep (concat / pad) ----------------
__global__ void prep_bias(
    const float* __restrict__ cls_b1, const float* __restrict__ ew_b1,
    const float* __restrict__ we_b1,  const float* __restrict__ cls_b2,
    const float* __restrict__ ew_b2,  const float* __restrict__ we_b2,
    float* b1ce, float* b1we, float* b2cls, float* b2ew, float* b2we) {
  int id = blockIdx.x * 256 + threadIdx.x;
  if (id < 1536) { b1ce[id] = (id < 768) ? cls_b1[id] : ew_b1[id - 768]; return; }
  id -= 1536;
  if (id < 768) { b1we[id] = we_b1[id]; return; }
  id -= 768;
  if (id < 768) { b2cls[id] = (id < 744) ? cls_b2[id] : 0.f; return; }
  id -= 768;
  if (id < 128) { b2ew[id] = (id < 124) ? ew_b2[id] : 0.f; return; }
  id -= 128;
  if (id < 128) { b2we[id] = (id < 124) ? we_b2[id] : 0.f; return; }
}

// ---------------- GEMM core: 128x128 tile, BK=64, 4 waves 2x2, XOR-swizzled LDS ----------------
// LDS layout: logical (row, c8) lives at physical c8p = c8 ^ (row&7)  [c8 = 8-elem group 0..7]
// -> every ds_read_b128 spreads 8 lanes per 16B bank-column (HW minimum, conflict-free).
// Staging permutes the *global* source per lane since global_load_lds's LDS side is rigid.
__device__ __forceinline__ void gemm_core(
    const u16* A0, const u16* A1, const u16* A2, int lda,
    const u16* B0, const u16* B1, const u16* B2,   // pre-offset by bn*K
    int npass, int K, int bm, int tid, u16* sA, u16* sB, f32x4 acc[4][4]) {
  const int lane = tid & 63;
  const int wv = tid >> 6;
  const int wr = wv >> 1, wc = wv & 1;
  const int sr = lane >> 3;                        // staging row within 8-row group
  const int sc = (((lane & 7) ^ sr) << 3);         // swizzled source col group
  for (int p = 0; p < npass; ++p) {
    const u16* A = (p == 0) ? A0 : ((p == 1) ? A1 : A2);
    const u16* Bp = (p == 0) ? B0 : ((p == 1) ? B1 : B2);
    const u16* gA = A + (size_t)(bm + wv * 32 + sr) * lda + sc;
    const u16* gB = Bp + (size_t)(wv * 32 + sr) * K + sc;
    u16* lA = sA + (wv * 32) * 64;
    u16* lB = sB + (wv * 32) * 64;
    for (int kt = 0; kt < K; kt += 64) {
#pragma unroll
      for (int s = 0; s < 4; ++s) {
        g2l16(gA + (size_t)(s * 8) * lda + kt, lA + s * 8 * 64);
        g2l16(gB + (size_t)(s * 8) * K + kt, lB + s * 8 * 64);
      }
      __syncthreads();
#pragma unroll
      for (int ks = 0; ks < 2; ++ks) {
        const int co = ((ks * 4 + (lane >> 4)) ^ (lane & 7)) * 8;  // row&7 == lane&7 for all frags
        short8 av[4], bv[4];
#pragma unroll
        for (int i = 0; i < 4; i++)
          av[i] = *(const short8*)(sA + (wr * 64 + i * 16 + (lane & 15)) * 64 + co);
#pragma unroll
        for (int j = 0; j < 4; j++)
          bv[j] = *(const short8*)(sB + (wc * 64 + j * 16 + (lane & 15)) * 64 + co);
#pragma unroll
        for (int i = 0; i < 4; i++)
#pragma unroll
          for (int j = 0; j < 4; j++)
            acc[i][j] = __builtin_amdgcn_mfma_f32_16x16x32_bf16(av[i], bv[j], acc[i][j], 0, 0, 0);
      }
      __syncthreads();
    }
  }
}

// XCD/L2 swizzle: grid = NC*128 1D. xcd=bid&7 owns a contiguous band of 16 row-chunks;
// within: 8-row sub-bands, rows fastest -> per-XCD working set (A band + hot B) ~ L2 size.
__device__ __forceinline__ void decode_bid(int bid, int NC, int& bm, int& bn) {
  const int xcd = bid & 7, slot = bid >> 3;
  const int per = NC << 3;
  const int sub = slot / per, rem = slot - sub * per;
  const int colu = rem >> 3, rowIn = rem & 7;
  bm = ((xcd << 4) + (sub << 3) + rowIn) << 7;
  bn = colu << 7;
}

// MODE 0: gelu -> bf16    MODE 2: gelu -> bf16 hi + bf16 lo
template <int MODE>
__global__ __launch_bounds__(256, 4) void gemm_k(
    const u16* A0, const u16* A1, const u16* A2, int lda,
    const u16* B0, const u16* B1, const u16* B2,
    int npass, int K, const float* __restrict__ bias,
    void* out0, void* out1, int ldc, int NC) {
  __shared__ u16 sA[128 * 64];
  __shared__ u16 sB[128 * 64];
  const int tid = threadIdx.x;
  const int lane = tid & 63;
  const int wr = (tid >> 6) >> 1, wc = (tid >> 6) & 1;
  int bm, bn;
  decode_bid(blockIdx.x, NC, bm, bn);

  f32x4 acc[4][4];
#pragma unroll
  for (int i = 0; i < 4; i++)
#pragma unroll
    for (int j = 0; j < 4; j++) acc[i][j] = f32x4{0.f, 0.f, 0.f, 0.f};

  const size_t bo = (size_t)bn * K;
  gemm_core(A0, A1, A2, lda, B0 + bo, B1 ? B1 + bo : nullptr, B2 ? B2 + bo : nullptr,
            npass, K, bm, tid, sA, sB, acc);

  // C/D layout: col=lane&15, row=(lane>>4)*4+r  [verified m89/m91]
#pragma unroll
  for (int j = 0; j < 4; j++) {
    const int col = bn + wc * 64 + j * 16 + (lane & 15);
    const float bs = bias[col];
#pragma unroll
    for (int i = 0; i < 4; i++) {
      const int row0 = bm + wr * 64 + i * 16 + (lane >> 4) * 4;
#pragma unroll
      for (int r = 0; r < 4; r++) {
        float v = acc[i][j][r] + bs;
        const size_t idx = (size_t)(row0 + r) * ldc + col;
        float g = 0.5f * v * (1.0f + erff(v * 0.70710678118654752f));  // exact GELU
        u16 h = f2bf(g);
        ((u16*)out0)[idx] = h;
        if (MODE == 2) ((u16*)out1)[idx] = f2bf(g - bf2f(h));
      }
    }
  }
}

// fused fc2: colu 0..5 -> cls (bf16 out), colu 6 -> ew (f32), colu 7 -> we 3-pass split (f32)
__global__ __launch_bounds__(256, 4) void gemm2_fused(
    const u16* __restrict__ h_cls,                  // [16384][1536]: cls cols 0..767, ew cols 768..1535
    const u16* __restrict__ hwe_hi, const u16* __restrict__ hwe_lo,
    const u16* __restrict__ BT2cls, const u16* __restrict__ BT2ew,
    const u16* __restrict__ BT2we_hi, const u16* __restrict__ BT2we_lo,
    const float* __restrict__ b2cls, const float* __restrict__ b2ew,
    const float* __restrict__ b2we,
    u16* __restrict__ Lcls, float* __restrict__ Lew, float* __restrict__ Lwe) {
  __shared__ u16 sA[128 * 64];
  __shared__ u16 sB[128 * 64];
  const int tid = threadIdx.x;
  const int lane = tid & 63;
  const int wr = (tid >> 6) >> 1, wc = (tid >> 6) & 1;
  int bm, bn;
  decode_bid(blockIdx.x, 8, bm, bn);
  const int colu = bn >> 7;

  f32x4 acc[4][4];
#pragma unroll
  for (int i = 0; i < 4; i++)
#pragma unroll
    for (int j = 0; j < 4; j++) acc[i][j] = f32x4{0.f, 0.f, 0.f, 0.f};

  if (colu < 6) {
    gemm_core(h_cls, nullptr, nullptr, 1536, BT2cls + (size_t)bn * 768, nullptr, nullptr,
              1, 768, bm, tid, sA, sB, acc);
#pragma unroll
    for (int j = 0; j < 4; j++) {
      const int col = bn + wc * 64 + j * 16 + (lane & 15);
      const float bs = b2cls[col];
#pragma unroll
      for (int i = 0; i < 4; i++) {
        const int row0 = bm + wr * 64 + i * 16 + (lane >> 4) * 4;
#pragma unroll
        for (int r = 0; r < 4; r++)
          Lcls[(size_t)(row0 + r) * 768 + col] = f2bf(acc[i][j][r] + bs);
      }
    }
  } else {
    const bool is_ew = (colu == 6);
    if (is_ew)
      gemm_core(h_cls + 768, nullptr, nullptr, 1536, BT2ew, nullptr, nullptr,
                1, 768, bm, tid, sA, sB, acc);
    else
      gemm_core(hwe_hi, hwe_lo, hwe_hi, 768, BT2we_hi, BT2we_hi, BT2we_lo,
                3, 768, bm, tid, sA, sB, acc);
    float* o = is_ew ? Lew : Lwe;
    const float* bp = is_ew ? b2ew : b2we;
#pragma unroll
    for (int j = 0; j < 4; j++) {
      const int col = wc * 64 + j * 16 + (lane & 15);
      const float bs = bp[col];
#pragma unroll
      for (int i = 0; i < 4; i++) {
        const int row0 = bm + wr * 64 + i * 16 + (lane >> 4) * 4;
#pragma unroll
        for (int r = 0; r < 4; r++)
          o[(size_t)(row0 + r) * 128 + col] = acc[i][j][r] + bs;
      }
    }
  }
}

// ---------------- finalize: rank-select mask (== reference threshold), softmaxes, mixture ----------------
// keep_i  <=>  which_i >= n-th largest  <=>  #{j : w_j > w_i} < n   (ties keep both, same as ref)
__global__ __launch_bounds__(256) void finalize(
    const u16* __restrict__ Lcls,   // bf16 [B][768], expert e at cols e*6..e*6+5
    const float* __restrict__ Lwe,  // f32 [B][128]
    const float* __restrict__ Lew,  // f32 [B][128]
    const int* __restrict__ nexp, float* __restrict__ out) {
  const int bid = blockIdx.x;
  const int g = ((bid & 7) << 9) + (bid >> 3);      // XCD band matches gemm2's row mapping
  const int b = (g << 2) + (int)(threadIdx.x >> 6); // 4 rows/block, one wave each
  const int lane = threadIdx.x & 63;
  const float NEG = -3.0e38f;
  const float w0 = (lane < 124) ? Lwe[(size_t)b * 128 + lane] : NEG;
  const float w1 = (lane < 60) ? Lwe[(size_t)b * 128 + 64 + lane] : NEG;
  int r0 = 0, r1 = 0;
#pragma unroll
  for (int j = 0; j < 64; ++j) {
    float v = __shfl(w0, j, 64);
    r0 += (v > w0); r1 += (v > w1);
  }
#pragma unroll
  for (int j = 0; j < 64; ++j) {
    float v = __shfl(w1, j, 64);
    r0 += (v > w0); r1 += (v > w1);
  }
  int n = nexp[b];
  n = n < 1 ? 1 : (n > 124 ? 124 : n);
  const bool k0 = (lane < 124) && (r0 < n);
  const bool k1 = (lane < 60) && (r1 < n);
  float l0 = k0 ? Lew[(size_t)b * 128 + lane] : NEG;
  float l1 = k1 ? Lew[(size_t)b * 128 + 64 + lane] : NEG;
  float mx = fmaxf(l0, l1);
#pragma unroll
  for (int o = 32; o > 0; o >>= 1) mx = fmaxf(mx, __shfl_xor(mx, o, 64));
  float e0 = k0 ? __expf(l0 - mx) : 0.f;
  float e1 = k1 ? __expf(l1 - mx) : 0.f;
  float S = e0 + e1;
#pragma unroll
  for (int o = 32; o > 0; o >>= 1) S += __shfl_xor(S, o, 64);
  float a0 = 0, a1 = 0, a2 = 0, a3 = 0, a4 = 0, a5 = 0;
#pragma unroll
  for (int h = 0; h < 2; ++h) {
    int e = lane + h * 64;
    float we = h ? e1 : e0;
    if (we > 0.f) {
      const u16* lp = Lcls + (size_t)b * 768 + e * 6;
      float c0 = bf2f(lp[0]), c1 = bf2f(lp[1]), c2 = bf2f(lp[2]);
      float c3 = bf2f(lp[3]), c4 = bf2f(lp[4]), c5 = bf2f(lp[5]);
      float m = fmaxf(fmaxf(fmaxf(c0, c1), fmaxf(c2, c3)), fmaxf(c4, c5));
      float p0 = __expf(c0 - m), p1 = __expf(c1 - m), p2 = __expf(c2 - m);
      float p3 = __expf(c3 - m), p4 = __expf(c4 - m), p5 = __expf(c5 - m);
      float inv = we / (p0 + p1 + p2 + p3 + p4 + p5);
      a0 += p0 * inv; a1 += p1 * inv; a2 += p2 * inv;
      a3 += p3 * inv; a4 += p4 * inv; a5 += p5 * inv;
    }
  }
#pragma unroll
  for (int o = 32; o > 0; o >>= 1) {
    a0 += __shfl_xor(a0, o, 64); a1 += __shfl_xor(a1, o, 64);
    a2 += __shfl_xor(a2, o, 64); a3 += __shfl_xor(a3, o, 64);
    a4 += __shfl_xor(a4, o, 64); a5 += __shfl_xor(a5, o, 64);
  }
  if (lane < 6) {
    float v = (lane == 0) ? a0 : (lane == 1) ? a1 : (lane == 2) ? a2
              : (lane == 3) ? a3 : (lane == 4) ? a4 : a5;
    out[(size_t)b * 6 + lane] = v / S;
  }
}

__global__ void fill_sentinel(float* out, int n, float v) {
  int i = blockIdx.x * 256 + threadIdx.x;
  if (i < n) out[i] = v;
}

extern "C" void kernel_launch(void* const* d_in, const int* in_sizes, int n_in,
                              void* d_out, int out_size, void* d_ws, size_t ws_size,
                              hipStream_t stream) {
  const float* x = (const float*)d_in[0];
  const int* nexp = (const int*)d_in[1];
  const float* cls_w1 = (const float*)d_in[2];
  const float* cls_b1 = (const float*)d_in[3];
  const float* cls_w2 = (const float*)d_in[4];
  const float* cls_b2 = (const float*)d_in[5];
  const float* we_w1 = (const float*)d_in[6];
  const float* we_b1 = (const float*)d_in[7];
  const float* we_w2 = (const float*)d_in[8];
  const float* we_b2 = (const float*)d_in[9];
  const float* ew_w1 = (const float*)d_in[10];
  const float* ew_b1 = (const float*)d_in[11];
  const float* ew_w2 = (const float*)d_in[12];
  const float* ew_b2 = (const float*)d_in[13];
  float* out = (float*)d_out;
  char* ws = (char*)d_ws;

  if (ws_size < WS_NEED) {  // diagnosable failure: absmax ~12345
    fill_sentinel<<<(out_size + 255) / 256, 256, 0, stream>>>(out, out_size, 12345.0f);
    return;
  }

  u16* xhi = (u16*)(ws + OFF_XHI);
  u16* xlo = (u16*)(ws + OFF_XLO);
  u16* Lcls = (u16*)(ws + OFF_LCLS);
  float* Lwe = (float*)(ws + OFF_LWE);
  float* Lew = (float*)(ws + OFF_LEW);
  u16* BT1 = (u16*)(ws + OFF_BT1);
  u16* BTwe_hi = (u16*)(ws + OFF_BTWE_HI);
  u16* BTwe_lo = (u16*)(ws + OFF_BTWE_LO);
  u16* BT2cls = (u16*)(ws + OFF_BT2CLS);
  u16* BT2ew = (u16*)(ws + OFF_BT2EW);
  u16* BT2we_hi = (u16*)(ws + OFF_BT2WE_HI);
  u16* BT2we_lo = (u16*)(ws + OFF_BT2WE_LO);
  float* b1ce = (float*)(ws + OFF_B1CE);
  float* b1we = (float*)(ws + OFF_B1WE);
  float* b2cls = (float*)(ws + OFF_B2CLS);
  float* b2ew = (float*)(ws + OFF_B2EW);
  float* b2we = (float*)(ws + OFF_B2WE);
  u16* h_clsew = (u16*)(ws + OFF_HCLSEW);
  u16* h_we_hi = (u16*)(ws + OFF_HWE_HI);
  u16* h_we_lo = (u16*)(ws + OFF_HWE_LO);

  transpose_w<<<dim3(12, 12, 6), 256, 0, stream>>>(cls_w1, ew_w1, we_w1, cls_w2, ew_w2, we_w2,
                                                   BT1, BTwe_hi, BTwe_lo, BT2cls, BT2ew,
                                                   BT2we_hi, BT2we_lo);
  prep_bias<<<13, 256, 0, stream>>>(cls_b1, ew_b1, we_b1, cls_b2, ew_b2, we_b2,
                                    b1ce, b1we, b2cls, b2ew, b2we);
  cvt_x_split<<<12288, 256, 0, stream>>>(x, xhi, xlo);
  // fc1 cls+ew (N=1536), gelu -> bf16
  gemm_k<0><<<1536, 256, 0, stream>>>(xhi, nullptr, nullptr, 768,
                                      BT1, nullptr, nullptr, 1, 768,
                                      b1ce, h_clsew, nullptr, 1536, 12);
  // fc1 we, 3-term split (hi*Whi + lo*Whi + hi*Wlo), gelu -> bf16 hi+lo
  gemm_k<2><<<768, 256, 0, stream>>>(xhi, xlo, xhi, 768,
                                     BTwe_hi, BTwe_hi, BTwe_lo, 3, 768,
                                     b1we, h_we_hi, h_we_lo, 768, 6);
  // fc2 all three heads in one dispatch (1024 blocks -> full chip)
  gemm2_fused<<<1024, 256, 0, stream>>>(h_clsew, h_we_hi, h_we_lo,
                                        BT2cls, BT2ew, BT2we_hi, BT2we_lo,
                                        b2cls, b2ew, b2we, Lcls, Lew, Lwe);
  finalize<<<4096, 256, 0, stream>>>(Lcls, Lwe, Lew, nexp, out);
}